// Round 1
// baseline (1676.424 us; speedup 1.0000x reference)
//
#include <hip/hip_runtime.h>
#include <math.h>

#define BB 8
#define NN 2048
#define FF 256
#define ALPHA 0.2f
#define NW (NN/32)   // packed words per row = 64

__device__ __forceinline__ float lrelu(float x){ return x > 0.f ? x : ALPHA*x; }

// ---------------------------------------------------------------- pack adj -> bits
__global__ void pack_adj(const int* __restrict__ adj, unsigned long long* __restrict__ packed,
                         long long total){
    long long idx = (long long)blockIdx.x*blockDim.x + threadIdx.x;
    long long stride = (long long)gridDim.x*blockDim.x;
    for (long long i = idx; i < total; i += stride){
        int bit = adj[i] > 0;
        unsigned long long m = __ballot(bit);
        if ((threadIdx.x & 63) == 0) packed[i >> 6] = m;
    }
}

// ---------------------------------------------------------------- Wh = h @ W  (per batch)
// block: 256 thr = 4 waves; tile 16 rows x 256 cols; K chunks of 32.
__global__ void gemm_h_w(const float* __restrict__ hin, const float* __restrict__ W,
                         float* __restrict__ Wh){
    __shared__ float Hs[16][33];
    __shared__ float Ws[32][256];
    int b  = blockIdx.y;
    int i0 = blockIdx.x * 16;
    int t  = threadIdx.x;
    int l  = t & 63, w = t >> 6;
    const float* hb = hin + (size_t)b*NN*FF;
    float acc[4][4] = {};
    for (int k0 = 0; k0 < FF; k0 += 32){
        __syncthreads();
        #pragma unroll
        for (int q = 0; q < 2; ++q){               // stage H tile [16][32]
            int e = t + 256*q;
            int r = e >> 5, k = e & 31;
            Hs[r][k] = hb[(size_t)(i0 + r)*FF + k0 + k];
        }
        #pragma unroll
        for (int q = 0; q < 8; ++q){               // stage W tile [32][256]
            int e4 = t + 256*q;
            int k = e4 >> 6, c = (e4 & 63) * 4;
            *(float4*)&Ws[k][c] = *(const float4*)&W[(size_t)(k0 + k)*FF + c];
        }
        __syncthreads();
        #pragma unroll
        for (int k = 0; k < 32; ++k){
            float4 wv = *(float4*)&Ws[k][4*l];
            float pr[4];
            #pragma unroll
            for (int r = 0; r < 4; ++r) pr[r] = Hs[4*w + r][k];   // LDS broadcast
            #pragma unroll
            for (int r = 0; r < 4; ++r){
                acc[r][0] = fmaf(pr[r], wv.x, acc[r][0]);
                acc[r][1] = fmaf(pr[r], wv.y, acc[r][1]);
                acc[r][2] = fmaf(pr[r], wv.z, acc[r][2]);
                acc[r][3] = fmaf(pr[r], wv.w, acc[r][3]);
            }
        }
    }
    #pragma unroll
    for (int r = 0; r < 4; ++r){
        float4 o = make_float4(acc[r][0], acc[r][1], acc[r][2], acc[r][3]);
        *(float4*)&Wh[((size_t)b*NN + i0 + 4*w + r)*FF + 4*l] = o;
    }
}

// ---------------------------------------------------------------- f1 = Wh.a1, f2 = Wh.a2 (one wave/row)
__global__ void fvec(const float* __restrict__ Wh, const float* __restrict__ Avec,
                     float* __restrict__ f1, float* __restrict__ f2){
    int row = blockIdx.x*4 + (threadIdx.x >> 6);
    int l = threadIdx.x & 63;
    float4 v  = *(const float4*)&Wh[(size_t)row*FF + 4*l];
    float4 a1 = *(const float4*)&Avec[4*l];
    float4 a2 = *(const float4*)&Avec[FF + 4*l];
    float d1 = v.x*a1.x + v.y*a1.y + v.z*a1.z + v.w*a1.w;
    float d2 = v.x*a2.x + v.y*a2.y + v.z*a2.z + v.w*a2.w;
    #pragma unroll
    for (int off = 32; off; off >>= 1){ d1 += __shfl_down(d1, off); d2 += __shfl_down(d2, off); }
    if (l == 0){ f1[row] = d1; f2[row] = d2; }
}

// ---------------------------------------------------------------- M = lrelu(max f1 + max f2), single block
__global__ void maxred(const float* __restrict__ f1, const float* __restrict__ f2,
                       float* __restrict__ Mout){
    int t = threadIdx.x;
    float m1 = -INFINITY, m2 = -INFINITY;
    for (int i = t; i < BB*NN; i += 256){ m1 = fmaxf(m1, f1[i]); m2 = fmaxf(m2, f2[i]); }
    __shared__ float s1[4], s2[4];
    #pragma unroll
    for (int off = 32; off; off >>= 1){ m1 = fmaxf(m1, __shfl_down(m1, off)); m2 = fmaxf(m2, __shfl_down(m2, off)); }
    if ((t & 63) == 0){ s1[t>>6] = m1; s2[t>>6] = m2; }
    __syncthreads();
    if (t == 0){
        float a = fmaxf(fmaxf(s1[0], s1[1]), fmaxf(s1[2], s1[3]));
        float b = fmaxf(fmaxf(s2[0], s2[1]), fmaxf(s2[2], s2[3]));
        Mout[0] = lrelu(a + b);   // lrelu monotone => >= max_ij lrelu(f1_i+f2_j)
    }
}

// ---------------------------------------------------------------- s_j partials: sum_i adj ? exp(e-M) : 0
// grid: (jt=8, it=16, b=8); thread owns one column j, walks 128 rows.
__global__ void spass(const unsigned int* __restrict__ packed, const float* __restrict__ f1,
                      const float* __restrict__ f2, const float* __restrict__ Mptr,
                      float* __restrict__ spart){
    int b = blockIdx.z, jt = blockIdx.x, it = blockIdx.y;
    int t = threadIdx.x;
    int j = jt*256 + t;
    float M = Mptr[0];
    float f2j = f2[(size_t)b*NN + j];
    const unsigned int* pb = packed + (size_t)b*NN*NW;
    const float* f1b = f1 + (size_t)b*NN;
    float s = 0.f;
    for (int ii = 0; ii < 128; ++ii){
        int i = it*128 + ii;
        unsigned int word = pb[(size_t)i*NW + (j >> 5)];
        float f1i = f1b[i];
        if ((word >> (j & 31)) & 1u)
            s += __expf(lrelu(f1i + f2j) - M);
    }
    spart[((size_t)b*16 + it)*NN + j] = s;
}

__global__ void scombine(const float* __restrict__ spart, float* __restrict__ sinv){
    int idx = blockIdx.x*256 + threadIdx.x;     // over B*N
    int b = idx >> 11, j = idx & (NN-1);
    float s = 0.f;
    #pragma unroll
    for (int it = 0; it < 16; ++it) s += spart[((size_t)b*16 + it)*NN + j];
    sinv[idx] = 1.0f / s;
}

// ---------------------------------------------------------------- hout = lrelu( P @ (Wh * sinv_row) )
// P recomputed on the fly per 16x32 tile; block tile 16 rows x 256 cols, K=N in chunks of 32.
__global__ void gemm_att(const float* __restrict__ Wh, const unsigned int* __restrict__ packed,
                         const float* __restrict__ f1, const float* __restrict__ f2,
                         const float* __restrict__ sinv, const float* __restrict__ Mptr,
                         float* __restrict__ hout){
    __shared__ float Ps[16][33];
    __shared__ float Ws[32][256];
    int b  = blockIdx.y;
    int i0 = blockIdx.x * 16;
    int t  = threadIdx.x;
    int l  = t & 63, w = t >> 6;
    float M = Mptr[0];
    const float* Whb = Wh + (size_t)b*NN*FF;
    const float* f1b = f1 + (size_t)b*NN;
    const float* f2b = f2 + (size_t)b*NN;
    const float* svb = sinv + (size_t)b*NN;
    const unsigned int* pb = packed + (size_t)b*NN*NW;
    float acc[4][4] = {};
    for (int j0 = 0; j0 < NN; j0 += 32){
        __syncthreads();
        #pragma unroll
        for (int q = 0; q < 2; ++q){               // P tile [16 rows][32 j]
            int e = t + 256*q;
            int r = e >> 5, k = e & 31;
            unsigned int word = pb[(size_t)(i0 + r)*NW + (j0 >> 5)];
            float p = 0.f;
            if ((word >> k) & 1u)
                p = __expf(lrelu(f1b[i0 + r] + f2b[j0 + k]) - M);
            Ps[r][k] = p;
        }
        #pragma unroll
        for (int q = 0; q < 8; ++q){               // Wh tile [32][256], rows pre-scaled by 1/s_j
            int e4 = t + 256*q;
            int k = e4 >> 6, c = (e4 & 63) * 4;
            float sv = svb[j0 + k];
            float4 v = *(const float4*)&Whb[(size_t)(j0 + k)*FF + c];
            v.x *= sv; v.y *= sv; v.z *= sv; v.w *= sv;
            *(float4*)&Ws[k][c] = v;
        }
        __syncthreads();
        #pragma unroll
        for (int k = 0; k < 32; ++k){
            float4 wv = *(float4*)&Ws[k][4*l];
            float pr[4];
            #pragma unroll
            for (int r = 0; r < 4; ++r) pr[r] = Ps[4*w + r][k];
            #pragma unroll
            for (int r = 0; r < 4; ++r){
                acc[r][0] = fmaf(pr[r], wv.x, acc[r][0]);
                acc[r][1] = fmaf(pr[r], wv.y, acc[r][1]);
                acc[r][2] = fmaf(pr[r], wv.z, acc[r][2]);
                acc[r][3] = fmaf(pr[r], wv.w, acc[r][3]);
            }
        }
    }
    #pragma unroll
    for (int r = 0; r < 4; ++r){
        float4 o;
        o.x = lrelu(acc[r][0]); o.y = lrelu(acc[r][1]);
        o.z = lrelu(acc[r][2]); o.w = lrelu(acc[r][3]);
        *(float4*)&hout[((size_t)b*NN + i0 + 4*w + r)*FF + 4*l] = o;
    }
}

// ----------------------------------------------------------------
extern "C" void kernel_launch(void* const* d_in, const int* in_sizes, int n_in,
                              void* d_out, int out_size, void* d_ws, size_t ws_size,
                              hipStream_t stream){
    const float* x     = (const float*)d_in[0];
    const int*   adj   = (const int*)  d_in[1];
    const float* W0    = (const float*)d_in[2];
    const float* Wrest = (const float*)d_in[3];
    const float* A     = (const float*)d_in[4];
    float* out = (float*)d_out;

    char* ws = (char*)d_ws;
    size_t off = 0;
    auto carve = [&](size_t bytes) -> void* {
        void* p = ws + off;
        off += (bytes + 255) & ~(size_t)255;
        return p;
    };
    unsigned int* packed = (unsigned int*)carve((size_t)BB*NN*NN/8);   // 4.2 MB of bits
    float* hbuf  = (float*)carve((size_t)BB*NN*FF*4);                  // layer activations
    float* Wh    = (float*)carve((size_t)BB*NN*FF*4);
    float* f1    = (float*)carve((size_t)BB*NN*4);
    float* f2    = (float*)carve((size_t)BB*NN*4);
    float* sinv  = (float*)carve((size_t)BB*NN*4);
    float* spart = (float*)carve((size_t)BB*16*NN*4);
    float* Mbuf  = (float*)carve(256);

    pack_adj<<<2048, 256, 0, stream>>>(adj, (unsigned long long*)packed, (long long)BB*NN*NN);

    const float* hin = x;
    for (int layer = 0; layer < 4; ++layer){
        const float* Wl = (layer == 0) ? W0 : (Wrest + (size_t)(layer-1)*FF*FF);
        const float* Al = A + (size_t)layer*2*FF;
        gemm_h_w<<<dim3(NN/16, BB), 256, 0, stream>>>(hin, Wl, Wh);
        fvec   <<<BB*NN/4, 256, 0, stream>>>(Wh, Al, f1, f2);
        maxred <<<1, 256, 0, stream>>>(f1, f2, Mbuf);
        spass  <<<dim3(8, 16, BB), 256, 0, stream>>>(packed, f1, f2, Mbuf, spart);
        scombine<<<BB*NN/256, 256, 0, stream>>>(spart, sinv);
        float* hout = (layer == 3) ? out : hbuf;    // gemm_att never reads hin/hbuf, safe to overwrite
        gemm_att<<<dim3(NN/16, BB), 256, 0, stream>>>(Wh, packed, f1, f2, sinv, Mbuf, hout);
        hin = hout;
    }
}

// Round 2
// 576.266 us; speedup vs baseline: 2.9091x; 2.9091x over previous
//
#include <hip/hip_runtime.h>
#include <math.h>

#define BB 8
#define NN 2048
#define FF 256
#define NW 64            // packed u32 words per adjacency row
#define ALPHA 0.2f

typedef _Float16 f16x8 __attribute__((ext_vector_type(8)));
typedef float    f32x4 __attribute__((ext_vector_type(4)));

__device__ __forceinline__ float lrelu(float x){ return fmaxf(x, ALPHA*x); }

// ---------------------------------------------------------------- pack adj bits + x->f16 + zero s
__global__ void pack_adj(const int* __restrict__ adj, unsigned long long* __restrict__ packed,
                         const float* __restrict__ x, _Float16* __restrict__ h0,
                         float* __restrict__ s){
    long long idx = (long long)blockIdx.x*blockDim.x + threadIdx.x;
    long long stride = (long long)gridDim.x*blockDim.x;
    const long long total = (long long)BB*NN*NN;
    for (long long i = idx; i < total; i += stride){
        unsigned long long m = __ballot(adj[i] > 0);
        if ((threadIdx.x & 63) == 0) packed[i >> 6] = m;
    }
    const long long nx4 = (long long)BB*NN*FF/4;
    for (long long i = idx; i < nx4; i += stride){
        float4 v = ((const float4*)x)[i];
        union { _Float16 h[4]; unsigned long long u; } cv;
        cv.h[0] = (_Float16)v.x; cv.h[1] = (_Float16)v.y;
        cv.h[2] = (_Float16)v.z; cv.h[3] = (_Float16)v.w;
        ((unsigned long long*)h0)[i] = cv.u;
    }
    for (long long i = idx; i < BB*NN; i += stride) s[i] = 0.f;
}

// ---------------------------------------------------------------- W (fp32 [k][c]) -> Wt (f16 [c][k]), 4 layers
__global__ void prep_w(const float* __restrict__ W0, const float* __restrict__ Wrest,
                       _Float16* __restrict__ Wt){
    __shared__ _Float16 Ls[64][66];
    int layer = blockIdx.z;
    int c0 = blockIdx.x * 64, k0 = blockIdx.y * 64;
    const float* Win = (layer == 0) ? W0 : (Wrest + (size_t)(layer-1)*FF*FF);
    int t = threadIdx.x;
    for (int it = 0; it < 4; ++it){
        int idx = it*256 + t;
        int r = idx >> 4, c4 = (idx & 15) * 4;
        float4 v = *(const float4*)&Win[(size_t)(k0 + r)*FF + c0 + c4];
        Ls[c4+0][r] = (_Float16)v.x; Ls[c4+1][r] = (_Float16)v.y;
        Ls[c4+2][r] = (_Float16)v.z; Ls[c4+3][r] = (_Float16)v.w;
    }
    __syncthreads();
    int c = t >> 2, jch = t & 3;
    const unsigned* lp = (const unsigned*)&Ls[c][jch*16];
    int4 o0 = make_int4(lp[0], lp[1], lp[2], lp[3]);
    int4 o1 = make_int4(lp[4], lp[5], lp[6], lp[7]);
    _Float16* dst = Wt + ((size_t)layer*FF + c0 + c)*FF + k0 + jch*16;
    *(int4*)dst = o0;
    *(int4*)(dst + 8) = o1;
}

// ---------------------------------------------------------------- Wh = h @ W (f16 MFMA) + fused f1,f2
__global__ __launch_bounds__(512,2) void gemm_hw(const _Float16* __restrict__ hin,
        const _Float16* __restrict__ Wt, const float* __restrict__ Avec,
        _Float16* __restrict__ Wh, float* __restrict__ f1, float* __restrict__ f2){
    __shared__ float fred[2][64][4];
    int t = threadIdx.x, l = t & 63, wid = t >> 6;
    int wr = wid >> 2, wc = wid & 3;
    int lg = l >> 4, lr = l & 15;
    size_t i0 = (size_t)blockIdx.x * 64;
    f32x4 acc[2][4] = {};
    for (int k0 = 0; k0 < FF; k0 += 32){
        f16x8 a[2], bf[4];
        #pragma unroll
        for (int m = 0; m < 2; ++m){
            int4 v = *(const int4*)&hin[(i0 + wr*32 + m*16 + lr)*FF + k0 + lg*8];
            a[m] = *(f16x8*)&v;
        }
        #pragma unroll
        for (int n = 0; n < 4; ++n){
            int4 v = *(const int4*)&Wt[(size_t)(wc*64 + n*16 + lr)*FF + k0 + lg*8];
            bf[n] = *(f16x8*)&v;
        }
        #pragma unroll
        for (int m = 0; m < 2; ++m)
            #pragma unroll
            for (int n = 0; n < 4; ++n)
                acc[m][n] = __builtin_amdgcn_mfma_f32_16x16x32_f16(a[m], bf[n], acc[m][n], 0, 0, 0);
    }
    // store Wh (f16) + fused f1/f2 reduction (fp32 exact from accumulators)
    float a1v[4], a2v[4];
    #pragma unroll
    for (int n = 0; n < 4; ++n){
        a1v[n] = Avec[wc*64 + n*16 + lr];
        a2v[n] = Avec[FF + wc*64 + n*16 + lr];
    }
    #pragma unroll
    for (int m = 0; m < 2; ++m){
        #pragma unroll
        for (int q = 0; q < 4; ++q){
            size_t row = i0 + wr*32 + m*16 + lg*4 + q;
            float p1 = 0.f, p2 = 0.f;
            #pragma unroll
            for (int n = 0; n < 4; ++n){
                float v = acc[m][n][q];
                Wh[row*FF + wc*64 + n*16 + lr] = (_Float16)v;
                p1 = fmaf(v, a1v[n], p1);
                p2 = fmaf(v, a2v[n], p2);
            }
            #pragma unroll
            for (int msk = 1; msk < 16; msk <<= 1){
                p1 += __shfl_xor(p1, msk);
                p2 += __shfl_xor(p2, msk);
            }
            if (lr == 0){
                fred[0][wr*32 + m*16 + lg*4 + q][wc] = p1;
                fred[1][wr*32 + m*16 + lg*4 + q][wc] = p2;
            }
        }
    }
    __syncthreads();
    if (t < 128){
        int row = t & 63, f = t >> 6;
        float v = fred[f][row][0] + fred[f][row][1] + fred[f][row][2] + fred[f][row][3];
        (f ? f2 : f1)[i0 + row] = v;
    }
}

// ---------------------------------------------------------------- Wh (f16 [b][j][c]) -> WhT (f16 [b][c][j])
__global__ void transpose_wh(const _Float16* __restrict__ Wh, _Float16* __restrict__ WhT){
    __shared__ _Float16 Ls[64][66];
    int jt = blockIdx.x, ct = blockIdx.y, b = blockIdx.z;
    int j0 = jt*64, c0 = ct*64;
    int t = threadIdx.x;
    const _Float16* src = Wh + (size_t)b*NN*FF;
    for (int it = 0; it < 2; ++it){
        int idx = it*256 + t;
        int r = idx >> 3, ch = idx & 7;
        int4 v = *(const int4*)&src[(size_t)(j0 + r)*FF + c0 + ch*8];
        const _Float16* hv = (const _Float16*)&v;
        #pragma unroll
        for (int e = 0; e < 8; ++e) Ls[ch*8 + e][r] = hv[e];
    }
    __syncthreads();
    int c = t >> 2, jch = t & 3;
    const unsigned* lp = (const unsigned*)&Ls[c][jch*16];
    int4 o0 = make_int4(lp[0], lp[1], lp[2], lp[3]);
    int4 o1 = make_int4(lp[4], lp[5], lp[6], lp[7]);
    _Float16* dst = WhT + ((size_t)b*FF + c0 + c)*NN + j0 + jch*16;
    *(int4*)dst = o0;
    *(int4*)(dst + 8) = o1;
}

// ---------------------------------------------------------------- s_j = sum_i adj ? exp(lrelu(f1_i+f2_j)) : 0
__global__ void spass(const unsigned* __restrict__ packed, const float* __restrict__ f1,
                      const float* __restrict__ f2, float* __restrict__ s){
    int jt = blockIdx.x, it = blockIdx.y, b = blockIdx.z;
    int j = jt*256 + threadIdx.x;
    const unsigned* pb = packed + (size_t)b*NN*NW;
    const float* f1b = f1 + b*NN;
    float f2j = f2[b*NN + j];
    int jw = j >> 5; unsigned jb = 1u << (j & 31);
    float acc = 0.f;
    for (int ii = 0; ii < 256; ++ii){
        int i = it*256 + ii;
        unsigned w = pb[(size_t)i*NW + jw];
        float e = f1b[i] + f2j;
        e = fmaxf(e, ALPHA*e);
        if (w & jb) acc += __expf(e);
    }
    atomicAdd(&s[b*NN + j], acc);
}

// ---------------------------------------------------------------- g = -ln(s); re-zero s for next layer
__global__ void finish_s(float* __restrict__ s, float* __restrict__ g){
    int i = blockIdx.x*256 + threadIdx.x;
    g[i] = -__logf(s[i]);
    s[i] = 0.f;
}

// ---------------------------------------------------------------- hout = lrelu( P' @ Wh ), P' on the fly
__global__ __launch_bounds__(512,2) void gemm_att(const _Float16* __restrict__ WhT,
        const unsigned long long* __restrict__ packed64, const float* __restrict__ f1,
        const float* __restrict__ f2, const float* __restrict__ g,
        _Float16* __restrict__ hnext, float* __restrict__ out, int last){
    __shared__ char Bs[32*1024];
    int t = threadIdx.x, l = t & 63, wid = t >> 6;
    int wr = wid >> 2, wc = wid & 3;
    int lg = l >> 4, lr = l & 15;
    int bid = blockIdx.x;
    int b = bid >> 5, i0 = (bid & 31) << 6;
    const _Float16* WhTb = WhT + (size_t)b*FF*NN;
    const unsigned long long* pb = packed64 + (size_t)b*NN*(NW/2);
    const float* f1b = f1 + b*NN;
    const float* f2b = f2 + b*NN;
    const float* gb  = g  + b*NN;
    int irow[2]; float f1v[2];
    #pragma unroll
    for (int m = 0; m < 2; ++m){
        irow[m] = i0 + wr*32 + m*16 + lr;
        f1v[m] = f1b[irow[m]];
    }
    f32x4 acc[2][4] = {};
    for (int ks = 0; ks < 32; ++ks){
        int j0 = ks*64;
        __syncthreads();
        #pragma unroll
        for (int q = 0; q < 4; ++q){
            int idx = q*512 + t;
            int col = idx >> 3, ch = idx & 7;
            int4 v = *(const int4*)&WhTb[(size_t)col*NN + j0 + ch*8];
            *(int4*)(Bs + (col<<7) + ((ch<<4) ^ ((col&7)<<4))) = v;   // T2 swizzle (write side)
        }
        __syncthreads();
        // ---- A fragments (P' = exp(lrelu(f1+f2) - ln s), masked) in MFMA layout
        f16x8 pa[2][2];
        unsigned long long w64[2];
        w64[0] = pb[(size_t)irow[0]*32 + ks];
        w64[1] = pb[(size_t)irow[1]*32 + ks];
        #pragma unroll
        for (int kk = 0; kk < 2; ++kk){
            int jb = j0 + kk*32 + lg*8;
            float4 fa = *(const float4*)&f2b[jb];
            float4 fb = *(const float4*)&f2b[jb+4];
            float4 ga = *(const float4*)&gb[jb];
            float4 gc = *(const float4*)&gb[jb+4];
            float fv[8] = {fa.x,fa.y,fa.z,fa.w,fb.x,fb.y,fb.z,fb.w};
            float gv[8] = {ga.x,ga.y,ga.z,ga.w,gc.x,gc.y,gc.z,gc.w};
            #pragma unroll
            for (int m = 0; m < 2; ++m){
                #pragma unroll
                for (int e = 0; e < 8; ++e){
                    float xv = f1v[m] + fv[e];
                    xv = fmaxf(xv, ALPHA*xv);
                    float p = __expf(xv + gv[e]);
                    int bit = (int)((w64[m] >> (kk*32 + lg*8 + e)) & 1ull);
                    pa[m][kk][e] = (_Float16)(bit ? p : 0.f);
                }
            }
        }
        // ---- B fragments from LDS (swizzled read) + MFMA
        #pragma unroll
        for (int n = 0; n < 4; ++n){
            int col = wc*64 + n*16 + lr;
            #pragma unroll
            for (int kk = 0; kk < 2; ++kk){
                int koff = kk*64 + lg*16;
                f16x8 bf = *(const f16x8*)(Bs + (col<<7) + (koff ^ ((col&7)<<4)));
                #pragma unroll
                for (int m = 0; m < 2; ++m)
                    acc[m][n] = __builtin_amdgcn_mfma_f32_16x16x32_f16(pa[m][kk], bf, acc[m][n], 0, 0, 0);
            }
        }
    }
    size_t obase = (size_t)b*NN*FF;
    #pragma unroll
    for (int m = 0; m < 2; ++m){
        #pragma unroll
        for (int q = 0; q < 4; ++q){
            size_t row = i0 + wr*32 + m*16 + lg*4 + q;
            #pragma unroll
            for (int n = 0; n < 4; ++n){
                int col = wc*64 + n*16 + lr;
                float v = lrelu(acc[m][n][q]);
                if (last) out[obase + row*FF + col] = v;
                else      hnext[obase + row*FF + col] = (_Float16)v;
            }
        }
    }
}

// ----------------------------------------------------------------
extern "C" void kernel_launch(void* const* d_in, const int* in_sizes, int n_in,
                              void* d_out, int out_size, void* d_ws, size_t ws_size,
                              hipStream_t stream){
    const float* x     = (const float*)d_in[0];
    const int*   adj   = (const int*)  d_in[1];
    const float* W0    = (const float*)d_in[2];
    const float* Wrest = (const float*)d_in[3];
    const float* A     = (const float*)d_in[4];
    float* out = (float*)d_out;

    char* ws = (char*)d_ws;
    size_t off = 0;
    auto carve = [&](size_t bytes) -> void* {
        void* p = ws + off;
        off += (bytes + 255) & ~(size_t)255;
        return p;
    };
    unsigned long long* packed = (unsigned long long*)carve((size_t)BB*NN*NN/8);
    _Float16* hA   = (_Float16*)carve((size_t)BB*NN*FF*2);
    _Float16* hB   = (_Float16*)carve((size_t)BB*NN*FF*2);
    _Float16* Wh   = (_Float16*)carve((size_t)BB*NN*FF*2);
    _Float16* WhT  = (_Float16*)carve((size_t)BB*NN*FF*2);
    _Float16* Wt   = (_Float16*)carve((size_t)4*FF*FF*2);
    float* f1 = (float*)carve((size_t)BB*NN*4);
    float* f2 = (float*)carve((size_t)BB*NN*4);
    float* s  = (float*)carve((size_t)BB*NN*4);
    float* g  = (float*)carve((size_t)BB*NN*4);

    pack_adj<<<2048, 256, 0, stream>>>(adj, packed, x, hA, s);
    prep_w<<<dim3(4,4,4), 256, 0, stream>>>(W0, Wrest, Wt);

    _Float16* bufs[2] = {hA, hB};
    const _Float16* hin = hA;
    for (int layer = 0; layer < 4; ++layer){
        const float* Al = A + (size_t)layer*2*FF;
        gemm_hw<<<256, 512, 0, stream>>>(hin, Wt + (size_t)layer*FF*FF, Al, Wh, f1, f2);
        transpose_wh<<<dim3(32,4,8), 256, 0, stream>>>(Wh, WhT);
        spass<<<dim3(8,8,8), 256, 0, stream>>>((const unsigned*)packed, f1, f2, s);
        finish_s<<<64, 256, 0, stream>>>(s, g);
        int last = (layer == 3);
        _Float16* hnext = bufs[(layer + 1) & 1];
        gemm_att<<<256, 512, 0, stream>>>(WhT, packed, f1, f2, g, hnext, out, last);
        hin = hnext;
    }
}